// Round 9
// baseline (207.341 us; speedup 1.0000x reference)
//
#include <hip/hip_runtime.h>
#include <math.h>

// Problem constants
constexpr int NROI = 2048;  // N
constexpr int CDIM = 1024;  // C
constexpr int NG   = 16;    // groups
constexpr int DH   = 64;    // per-group dim

typedef __attribute__((ext_vector_type(8))) short short8;    // 8 bf16 (4 VGPRs)
typedef __attribute__((ext_vector_type(4))) float floatx4;   // MFMA C/D frag

#define MFMA_BF16(a, b, c) __builtin_amdgcn_mfma_f32_16x16x32_bf16((a), (b), (c), 0, 0, 0)

// fp32 -> bf16 round-to-nearest-even
__device__ __forceinline__ short f2bf(float f) {
  unsigned u = __float_as_uint(f);
  unsigned r = 0x7fffu + ((u >> 16) & 1u);
  return (short)((u + r) >> 16);
}
__device__ __forceinline__ float bf2f(unsigned short u) {
  return __uint_as_float(((unsigned)u) << 16);
}
__device__ __forceinline__ unsigned pack2(float a, float b) {
  return (unsigned)(unsigned short)f2bf(a) | ((unsigned)(unsigned short)f2bf(b) << 16);
}

// HW packed fp32->bf16 convert (RNE): dst.lo = bf16(lo), dst.hi = bf16(hi)
__device__ __forceinline__ unsigned cvtpk_bf16(float lo, float hi) {
  unsigned r;
  asm("v_cvt_pk_bf16_f32 %0, %1, %2" : "=v"(r) : "v"(lo), "v"(hi));
  return r;
}

// 8 fp32 -> short8 bf16 (RNE, bit-identical to pack2 path)
__device__ __forceinline__ short8 cvt8(float4 v0, float4 v1) {
  union { short8 s; unsigned u[4]; } r;
  r.u[0] = cvtpk_bf16(v0.x, v0.y);
  r.u[1] = cvtpk_bf16(v0.z, v0.w);
  r.u[2] = cvtpk_bf16(v1.x, v1.y);
  r.u[3] = cvtpk_bf16(v1.z, v1.w);
  return r.s;
}

// 2^x via v_exp_f32
__device__ __forceinline__ float fexp2(float x) {
#if __has_builtin(__builtin_amdgcn_exp2f)
  return __builtin_amdgcn_exp2f(x);
#else
  return __expf(x * 0.69314718056f);
#endif
}

// async global->LDS, 16B per lane; LDS dest = wave-uniform base + lane*16
typedef __attribute__((address_space(1))) void GV;
typedef __attribute__((address_space(3))) void LV;
__device__ __forceinline__ void gl2lds16(const void* g, void* l) {
  __builtin_amdgcn_global_load_lds((GV*)g, (LV*)l, 16, 0, 0);
}

// bf16 relu on a packed short8 (sign-bit based; exact)
__device__ __forceinline__ short8 brelu(short8 v) {
  union { short8 s; unsigned u[4]; } x; x.s = v;
#pragma unroll
  for (int i = 0; i < 4; ++i) {
    unsigned m = (x.u[i] >> 15) & 0x10001u;
    x.u[i] &= ~(m * 0xFFFFu);
  }
  return x.s;
}

// --- key-position permutation -------------------------------------------------
// Attention computes S^T = mfma(K, Q); P stays in-lane. The PV contraction is
// invariant under k-slot permutation, so V (zT) and the bias matrix store their
// key axis permuted so P packs into A-fragments with no cross-lane moves:
//   position p(k) within each 32-key block = ((k>>2)&3)*8 + ((k>>4)&1)*4 + (k&3)
__device__ __forceinline__ int keypos(int k) {
  return (k & ~31) | (((k >> 2) & 3) << 3) | (((k >> 4) & 1) << 2);
}

// ---------------- gemm1f: fused t0 + zT, fp32 inputs converted inline ----------------
// 64x64 double-buffered tile (R5/R7-verified structure); staging is
// register-staged (float4 load -> cvt_pk -> ds_write_b128) since inputs are
// fp32. blockIdx.x<16 -> t0 = relu(x)@W0^T+b0 (row-major); else
// zT = (x@Wout^T)^T (transposed, KEY-PERMUTED rows). grid (32,32).
// Epilogue additionally computes the iou+1e-6 bias matrix (16 keys/thread),
// replacing the old prep kernel's iou pass.
__global__ __launch_bounds__(256, 4) void gemm1f(
    const float* __restrict__ Xf, const float* __restrict__ W0f,
    const float* __restrict__ Woutf, const float* __restrict__ rois,
    const float* __restrict__ bias,
    short* __restrict__ outRM, short* __restrict__ outTR,
    unsigned short* __restrict__ biasb)
{
  __shared__ short As[2][8 * 512];
  __shared__ short Bs[2][8 * 512];
  const int t = threadIdx.x, w = t >> 6, lane = t & 63;
  const int wm = w >> 1, wn = w & 1;
  const int row0 = blockIdx.y * 64;
  const bool isW0 = blockIdx.x < 16;
  const int col0 = (blockIdx.x & 15) * 64;
  const float* Bf = isW0 ? W0f : Woutf;
  const int rlo = lane & 15, khi = (lane >> 4) * 8;
  const int arow = row0 + w * 16 + rlo;
  const int brow = col0 + w * 16 + rlo;

  floatx4 acc[2][2];
#pragma unroll
  for (int i = 0; i < 2; ++i)
#pragma unroll
    for (int j = 0; j < 2; ++j) acc[i][j] = (floatx4){0.f, 0.f, 0.f, 0.f};

  // stage k=0 (direct load+convert+write)
#pragma unroll
  for (int kh = 0; kh < 2; ++kh) {
    const float* pa = Xf + (size_t)arow * CDIM + kh * 32 + khi;
    const float* pb = Bf + (size_t)brow * CDIM + kh * 32 + khi;
    *(short8*)&As[0][(w * 2 + kh) * 512 + lane * 8] =
        cvt8(*(const float4*)pa, *(const float4*)(pa + 4));
    *(short8*)&Bs[0][(w * 2 + kh) * 512 + lane * 8] =
        cvt8(*(const float4*)pb, *(const float4*)(pb + 4));
  }
  __syncthreads();

  for (int it = 0; it < 16; ++it) {
    const int p = it & 1;
    // T14 split: issue next-tile loads EARLY (latency hides under MFMA)
    float4 la[2][2], lb[2][2];
    if (it < 15) {
      const int k1 = (it + 1) * 64;
#pragma unroll
      for (int kh = 0; kh < 2; ++kh) {
        const float* pa = Xf + (size_t)arow * CDIM + k1 + kh * 32 + khi;
        const float* pb = Bf + (size_t)brow * CDIM + k1 + kh * 32 + khi;
        la[kh][0] = *(const float4*)pa;  la[kh][1] = *(const float4*)(pa + 4);
        lb[kh][0] = *(const float4*)pb;  lb[kh][1] = *(const float4*)(pb + 4);
      }
    }
    // compute on buffer p (verified fragment/MFMA pattern)
#pragma unroll
    for (int kh = 0; kh < 2; ++kh) {
      short8 a[2], bf[2];
#pragma unroll
      for (int i = 0; i < 2; ++i) {
        a[i] = *(const short8*)&As[p][((wm * 2 + i) * 2 + kh) * 512 + lane * 8];
        if (isW0) a[i] = brelu(a[i]);
      }
#pragma unroll
      for (int j = 0; j < 2; ++j)
        bf[j] = *(const short8*)&Bs[p][((wn * 2 + j) * 2 + kh) * 512 + lane * 8];
#pragma unroll
      for (int i = 0; i < 2; ++i)
#pragma unroll
        for (int j = 0; j < 2; ++j)
          acc[i][j] = MFMA_BF16(a[i], bf[j], acc[i][j]);
    }
    // write-late: convert + ds_write into the other buffer
    if (it < 15) {
#pragma unroll
      for (int kh = 0; kh < 2; ++kh) {
        *(short8*)&As[1 - p][(w * 2 + kh) * 512 + lane * 8] = cvt8(la[kh][0], la[kh][1]);
        *(short8*)&Bs[1 - p][(w * 2 + kh) * 512 + lane * 8] = cvt8(lb[kh][0], lb[kh][1]);
      }
    }
    __syncthreads();
  }

  const int colL = lane & 15, qq = lane >> 4;
  if (isW0) {
    float bj[2];
    bj[0] = bias[col0 + wn * 32 + colL];
    bj[1] = bias[col0 + wn * 32 + 16 + colL];
#pragma unroll
    for (int i = 0; i < 2; ++i)
#pragma unroll
      for (int j = 0; j < 2; ++j)
#pragma unroll
        for (int r = 0; r < 4; ++r) {
          const int row = row0 + wm * 32 + i * 16 + qq * 4 + r;
          const int cc  = col0 + wn * 32 + j * 16 + colL;
          outRM[(size_t)row * CDIM + cc] = f2bf(acc[i][j][r] + bj[j]);
        }
  } else {
#pragma unroll
    for (int i = 0; i < 2; ++i)
#pragma unroll
      for (int j = 0; j < 2; ++j) {
        unsigned long long u =
            (unsigned long long)pack2(acc[i][j][0], acc[i][j][1]) |
            ((unsigned long long)pack2(acc[i][j][2], acc[i][j][3]) << 32);
        const int cc  = col0 + wn * 32 + j * 16 + colL;
        const int row = row0 + wm * 32 + i * 16 + qq * 4;   // 4-aligned key group
        *(unsigned long long*)&outTR[(size_t)cc * NROI + keypos(row)] = u;
      }
  }

  // ---- iou+1e-6 bias epilogue (verified math; 16 keys per thread) ----
  {
    const int tid = (blockIdx.y * 32 + blockIdx.x) * 256 + threadIdx.x;  // < 262144
    const int q   = tid >> 7;              // 2048 rows
    const int k0  = (tid & 127) * 16;      // 16 consecutive keys
    const float qx1 = rois[q * 5 + 1], qy1 = rois[q * 5 + 2];
    const float qx2 = rois[q * 5 + 3], qy2 = rois[q * 5 + 4];
    const float qa = (qx2 - qx1 + 1.f) * (qy2 - qy1 + 1.f);
#pragma unroll
    for (int b = 0; b < 4; ++b) {
      const int kk = k0 + b * 4;
      float v[4];
#pragma unroll
      for (int j = 0; j < 4; ++j) {
        const int k = kk + j;
        const float kx1 = rois[k * 5 + 1], ky1 = rois[k * 5 + 2];
        const float kx2 = rois[k * 5 + 3], ky2 = rois[k * 5 + 4];
        const float ka = (kx2 - kx1 + 1.f) * (ky2 - ky1 + 1.f);
        float iw = fminf(qx2, kx2) - fmaxf(qx1, kx1) + 1.f;
        float ih = fminf(qy2, ky2) - fmaxf(qy1, ky1) + 1.f;
        iw = fmaxf(iw, 0.f); ih = fmaxf(ih, 0.f);
        const float inter = iw * ih;
        v[j] = inter * __builtin_amdgcn_rcpf(qa + ka - inter) + 1e-6f;
      }
      uint2 u; u.x = pack2(v[0], v[1]); u.y = pack2(v[2], v[3]);
      *(uint2*)&biasb[(size_t)q * NROI + keypos(kk)] = u;
    }
  }
}

// ---------------- gemm2f: xb = relu(t0)@W1^T + b1, W1 fp32 converted inline ----------------
// A (t0b, bf16) staged via gl2lds16 (verified path); B (W1, fp32) register-staged.
// grid (16,32).
__global__ __launch_bounds__(256, 4) void gemm2f(
    const short* __restrict__ A, const float* __restrict__ W1f,
    const float* __restrict__ bias, short* __restrict__ outRM)
{
  __shared__ short As[2][8 * 512];
  __shared__ short Bs[2][8 * 512];
  const int t = threadIdx.x, w = t >> 6, lane = t & 63;
  const int wm = w >> 1, wn = w & 1;
  const int row0 = blockIdx.y * 64;
  const int col0 = blockIdx.x * 64;
  const int rlo = lane & 15, khi = (lane >> 4) * 8;
  const int brow = col0 + w * 16 + rlo;

  floatx4 acc[2][2];
#pragma unroll
  for (int i = 0; i < 2; ++i)
#pragma unroll
    for (int j = 0; j < 2; ++j) acc[i][j] = (floatx4){0.f, 0.f, 0.f, 0.f};

  // stage k=0
#pragma unroll
  for (int kh = 0; kh < 2; ++kh) {
    gl2lds16(A + (size_t)(row0 + w * 16 + rlo) * CDIM + kh * 32 + khi,
             &As[0][(w * 2 + kh) * 512]);
    const float* pb = W1f + (size_t)brow * CDIM + kh * 32 + khi;
    *(short8*)&Bs[0][(w * 2 + kh) * 512 + lane * 8] =
        cvt8(*(const float4*)pb, *(const float4*)(pb + 4));
  }
  __syncthreads();

  for (int it = 0; it < 16; ++it) {
    const int p = it & 1;
    float4 lb[2][2];
    if (it < 15) {
      const int k1 = (it + 1) * 64;
#pragma unroll
      for (int kh = 0; kh < 2; ++kh) {
        gl2lds16(A + (size_t)(row0 + w * 16 + rlo) * CDIM + k1 + kh * 32 + khi,
                 &As[1 - p][(w * 2 + kh) * 512]);
        const float* pb = W1f + (size_t)brow * CDIM + k1 + kh * 32 + khi;
        lb[kh][0] = *(const float4*)pb;  lb[kh][1] = *(const float4*)(pb + 4);
      }
    }
#pragma unroll
    for (int kh = 0; kh < 2; ++kh) {
      short8 a[2], bf[2];
#pragma unroll
      for (int i = 0; i < 2; ++i) {
        a[i] = brelu(*(const short8*)&As[p][((wm * 2 + i) * 2 + kh) * 512 + lane * 8]);
      }
#pragma unroll
      for (int j = 0; j < 2; ++j)
        bf[j] = *(const short8*)&Bs[p][((wn * 2 + j) * 2 + kh) * 512 + lane * 8];
#pragma unroll
      for (int i = 0; i < 2; ++i)
#pragma unroll
        for (int j = 0; j < 2; ++j)
          acc[i][j] = MFMA_BF16(a[i], bf[j], acc[i][j]);
    }
    if (it < 15) {
#pragma unroll
      for (int kh = 0; kh < 2; ++kh)
        *(short8*)&Bs[1 - p][(w * 2 + kh) * 512 + lane * 8] = cvt8(lb[kh][0], lb[kh][1]);
    }
    __syncthreads();
  }

  const int colL = lane & 15, qq = lane >> 4;
  float bj[2];
  bj[0] = bias[col0 + wn * 32 + colL];
  bj[1] = bias[col0 + wn * 32 + 16 + colL];
#pragma unroll
  for (int i = 0; i < 2; ++i)
#pragma unroll
    for (int j = 0; j < 2; ++j)
#pragma unroll
      for (int r = 0; r < 4; ++r) {
        const int row = row0 + wm * 32 + i * 16 + qq * 4 + r;
        const int cc  = col0 + wn * 32 + j * 16 + colL;
        outRM[(size_t)row * CDIM + cc] = f2bf(acc[i][j][r] + bj[j]);
      }
}

// ---------------- MFMA flash attention, v6 (R7-verified, verbatim) ----------------
// 16 waves = 4 key-quarters x 4 q-waves, 32 q/wave, 8 iters, double-buffered
// K/V staging; softmax denominator via ones-column MFMA (lands in oc layout).
__global__ __launch_bounds__(1024) void attn_bias(
    const short* __restrict__ Xb,             // (N,C) bf16 embedded x
    const short* __restrict__ ZTb,            // (C,N) bf16 V, transposed, key-permuted
    const unsigned short* __restrict__ biasb, // (N,N) bf16 iou+1e-6, key-permuted
    const float* __restrict__ bout,
    float* __restrict__ Out)
{
  // XCD-aware decode: lin%8 = XCD. XCD x hosts groups {2x, 2x+1}.
  const int lin  = blockIdx.x + 16 * blockIdx.y;   // 256 blocks
  const int xcd  = lin & 7;
  const int slot = lin >> 3;                       // 0..31
  const int g    = 2 * xcd + (slot >> 4);
  const int n0   = (slot & 15) * 128;

  const int t    = threadIdx.x;
  const int w    = t >> 6;
  const int qt   = w >> 2;      // key quarter 0..3 -> keys [qt*512, qt*512+512)
  const int wq   = w & 3;       // q-pair index: q rows [n0+wq*32, n0+wq*32+32)
  const int lane = t & 63;
  const int col  = lane & 15;
  const int qq   = lane >> 4;
  const int rlo  = col, khi = qq * 8;

  __shared__ short Kq[4][2][4096];  // [quarter][buf][8 frags x 512]
  __shared__ short Vq[4][2][4096];

  // Q fragments for the two 16-q subtiles
  short8 qf[2][2];
#pragma unroll
  for (int s = 0; s < 2; ++s) {
    const size_t qoff = (size_t)(n0 + wq * 32 + s * 16 + col) * CDIM + g * DH;
    qf[s][0] = *(const short8*)(Xb + qoff + qq * 8);
    qf[s][1] = *(const short8*)(Xb + qoff + 32 + qq * 8);
  }

  // constant ones B-fragment (bf16 1.0) for the denominator MFMA
  short8 ONES;
#pragma unroll
  for (int i = 0; i < 8; ++i) ONES[i] = (short)0x3F80;

  floatx4 oc[2][4];   // [sub][dt]
#pragma unroll
  for (int s = 0; s < 2; ++s)
#pragma unroll
    for (int dt = 0; dt < 4; ++dt) oc[s][dt] = (floatx4){0.f, 0.f, 0.f, 0.f};
  floatx4 lsA[2];     // denominator, same (qq,r) layout as oc rows
  lsA[0] = (floatx4){0.f, 0.f, 0.f, 0.f};
  lsA[1] = (floatx4){0.f, 0.f, 0.f, 0.f};

  const int kb = qt * 512;   // this quarter's key base

  // stage iter 0: wave wq stages key-subtile wq (both k/key halves)
#pragma unroll
  for (int kh = 0; kh < 2; ++kh) {
    gl2lds16(Xb + (size_t)(kb + wq * 16 + rlo) * CDIM + g * DH + kh * 32 + khi,
             &Kq[qt][0][(wq * 2 + kh) * 512]);
    gl2lds16(ZTb + (size_t)(g * DH + wq * 16 + rlo) * NROI + kb + kh * 32 + khi,
             &Vq[qt][0][(wq * 2 + kh) * 512]);
  }
  __syncthreads();

  const unsigned short* bq0 =
      biasb + (size_t)(n0 + wq * 32 + col) * NROI + kb + qq * 8;
  const unsigned short* bq1 = bq0 + (size_t)16 * NROI;

  for (int it = 0; it < 8; ++it) {
    const int p  = it & 1;
    const int m0 = kb + it * 64;

    // bias: four coalesced 16B loads (two per q-subtile), issued early
    union { short8 s8[4]; unsigned short h[32]; } BU;
    BU.s8[0] = *(const short8*)(bq0 + it * 64);
    BU.s8[1] = *(const short8*)(bq0 + it * 64 + 32);
    BU.s8[2] = *(const short8*)(bq1 + it * 64);
    BU.s8[3] = *(const short8*)(bq1 + it * 64 + 32);

    if (it + 1 < 8) {
      const int m1 = m0 + 64;
#pragma unroll
      for (int kh = 0; kh < 2; ++kh) {
        gl2lds16(Xb + (size_t)(m1 + wq * 16 + rlo) * CDIM + g * DH + kh * 32 + khi,
                 &Kq[qt][1 - p][(wq * 2 + kh) * 512]);
        gl2lds16(ZTb + (size_t)(g * DH + wq * 16 + rlo) * NROI + m1 + kh * 32 + khi,
                 &Vq[qt][1 - p][(wq * 2 + kh) * 512]);
      }
    }

    // QK + softmax-weight + pack, per 16-key column-tile ct; each K-frag pair
    // feeds BOTH q-subtiles (the LDS-read amortization).
    union { short8 s; unsigned u[4]; } U[2][2];   // [sub][kslot-half]
#pragma unroll
    for (int ct = 0; ct < 4; ++ct) {
      const short8 k0 = *(const short8*)&Kq[qt][p][(ct * 2 + 0) * 512 + lane * 8];
      const short8 k1 = *(const short8*)&Kq[qt][p][(ct * 2 + 1) * 512 + lane * 8];
#pragma unroll
      for (int s = 0; s < 2; ++s) {
        floatx4 z4 = (floatx4){0.f, 0.f, 0.f, 0.f};
        z4 = MFMA_BF16(k0, qf[s][0], z4);
        z4 = MFMA_BF16(k1, qf[s][1], z4);
        float pv0 = fexp2(z4[0] * 0.18033688011f) * bf2f(BU.h[s * 16 + ct * 4 + 0]);
        float pv1 = fexp2(z4[1] * 0.18033688011f) * bf2f(BU.h[s * 16 + ct * 4 + 1]);
        float pv2 = fexp2(z4[2] * 0.18033688011f) * bf2f(BU.h[s * 16 + ct * 4 + 2]);
        float pv3 = fexp2(z4[3] * 0.18033688011f) * bf2f(BU.h[s * 16 + ct * 4 + 3]);
        U[s][ct >> 1].u[(ct & 1) * 2 + 0] = cvtpk_bf16(pv0, pv1);
        U[s][ct >> 1].u[(ct & 1) * 2 + 1] = cvtpk_bf16(pv2, pv3);
      }
    }

    // denominator: rowsum of packed P via ones-column MFMA (static indices)
    lsA[0] = MFMA_BF16(U[0][0].s, ONES, lsA[0]);
    lsA[0] = MFMA_BF16(U[0][1].s, ONES, lsA[0]);
    lsA[1] = MFMA_BF16(U[1][0].s, ONES, lsA[1]);
    lsA[1] = MFMA_BF16(U[1][1].s, ONES, lsA[1]);

    // PV: each V-frag pair feeds both q-subtiles
#pragma unroll
    for (int dt = 0; dt < 4; ++dt) {
      const short8 v0 = *(const short8*)&Vq[qt][p][(dt * 2 + 0) * 512 + lane * 8];
      const short8 v1 = *(const short8*)&Vq[qt][p][(dt * 2 + 1) * 512 + lane * 8];
#pragma unroll
      for (int s = 0; s < 2; ++s) {
        oc[s][dt] = MFMA_BF16(U[s][0].s, v0, oc[s][dt]);
        oc[s][dt] = MFMA_BF16(U[s][1].s, v1, oc[s][dt]);
      }
    }
    __syncthreads();
  }

  // cross-quarter combine via LDS (K/V buffers dead). oc: lane-contiguous
  // [elem][wave12][lane] (conflict-free). lsA[s][r] is identical across the 16
  // lanes of a qq-group, so col==0 lanes store 32 floats per wave; readers hit
  // the same address per qq-group -> LDS broadcast.
  float* kbuf = (float*)&Kq[0][0][0];   // 16384 floats
  float* vbuf = (float*)&Vq[0][0][0];   // 16384 floats
  const int wslot = (qt - 1) * 4 + wq;  // 0..11 for quarters 1..3
  if (qt != 0) {
#pragma unroll
    for (int dt = 0; dt < 4; ++dt)
#pragma unroll
      for (int r = 0; r < 4; ++r) {
        kbuf[(dt * 4 + r) * 768 + wslot * 64 + lane] = oc[0][dt][r];
        vbuf[(dt * 4 + r) * 768 + wslot * 64 + lane] = oc[1][dt][r];
      }
    if (col == 0) {
#pragma unroll
      for (int s = 0; s < 2; ++s)
#pragma unroll
        for (int r = 0; r < 4; ++r)
          kbuf[12288 + wslot * 32 + s * 16 + qq * 4 + r] = lsA[s][r];
    }
  }
  __syncthreads();
  if (qt == 0) {
    float ls[2][4];
#pragma unroll
    for (int s = 0; s < 2; ++s)
#pragma unroll
      for (int r = 0; r < 4; ++r) ls[s][r] = lsA[s][r];
#pragma unroll
    for (int j = 0; j < 3; ++j) {
      const int ws = j * 4 + wq;
#pragma unroll
      for (int dt = 0; dt < 4; ++dt)
#pragma unroll
        for (int r = 0; r < 4; ++r) {
          oc[0][dt][r] += kbuf[(dt * 4 + r) * 768 + ws * 64 + lane];
          oc[1][dt][r] += vbuf[(dt * 4 + r) * 768 + ws * 64 + lane];
        }
#pragma unroll
      for (int s = 0; s < 2; ++s)
#pragma unroll
        for (int r = 0; r < 4; ++r)
          ls[s][r] += kbuf[12288 + ws * 32 + s * 16 + qq * 4 + r];
    }
#pragma unroll
    for (int s = 0; s < 2; ++s) {
      float rinv[4];
#pragma unroll
      for (int r = 0; r < 4; ++r)
        rinv[r] = __builtin_amdgcn_rcpf(ls[s][r]);
#pragma unroll
      for (int dt = 0; dt < 4; ++dt) {
        const float bo = bout[g * DH + dt * 16 + col];
#pragma unroll
        for (int r = 0; r < 4; ++r)
          Out[(size_t)(n0 + wq * 32 + s * 16 + qq * 4 + r) * CDIM + g * DH +
              dt * 16 + col] = oc[s][dt][r] * rinv[r] + bo;
      }
    }
  }
}

extern "C" void kernel_launch(void* const* d_in, const int* in_sizes, int n_in,
                              void* d_out, int out_size, void* d_ws, size_t ws_size,
                              hipStream_t stream) {
  const float* in_x = (const float*)d_in[0];
  const float* rois = (const float*)d_in[1];
  const float* W0   = (const float*)d_in[2];
  const float* b0   = (const float*)d_in[3];
  const float* W1   = (const float*)d_in[4];
  const float* b1   = (const float*)d_in[5];
  const float* Wout = (const float*)d_in[6];  // (G,D,C) flat == (C,C) row-major
  const float* bout = (const float*)d_in[7];
  char* w8 = (char*)d_ws;

  // ws layout (22 MB):
  //   [0,4M)   xb (gemm2 out, attn's Q/K input)
  //   [10,14M) zT (bf16 V^T, key-permuted)
  //   [14,22M) biasb (bf16 iou+1e-6, key-permuted)
  // t0b (bf16 gemm1 out) lives in d_out; attn overwrites d_out with final fp32.
  short* xb    = (short*)w8;
  short* zT    = (short*)(w8 + ((size_t)10 << 20));
  unsigned short* biasb = (unsigned short*)(w8 + ((size_t)14 << 20));
  short* t0b = (short*)d_out;

  // 1) fused 64x64: t0 = relu(x)@W0^T+b0, zT = (x@Wout^T)^T, + iou bias epilogue
  gemm1f<<<dim3(32, 32), 256, 0, stream>>>(in_x, W0, Wout, rois, b0,
                                           t0b, zT, biasb);
  // 2) 64x64: xb = relu(t0)@W1^T + b1 (W1 converted inline)
  gemm2f<<<dim3(16, 32), 256, 0, stream>>>(t0b, W1, b1, xb);
  // 3) flash attention v6 (R7-verified verbatim)
  attn_bias<<<dim3(16, 16), 1024, 0, stream>>>(xb, zT, biasb, bout,
                                               (float*)d_out);
}

// Round 10
// 180.820 us; speedup vs baseline: 1.1467x; 1.1467x over previous
//
#include <hip/hip_runtime.h>
#include <math.h>

// Problem constants
constexpr int NROI = 2048;  // N
constexpr int CDIM = 1024;  // C
constexpr int NG   = 16;    // groups
constexpr int DH   = 64;    // per-group dim

typedef __attribute__((ext_vector_type(8))) short short8;    // 8 bf16 (4 VGPRs)
typedef __attribute__((ext_vector_type(4))) float floatx4;   // MFMA C/D frag

#define MFMA_BF16(a, b, c) __builtin_amdgcn_mfma_f32_16x16x32_bf16((a), (b), (c), 0, 0, 0)

// fp32 -> bf16 round-to-nearest-even
__device__ __forceinline__ short f2bf(float f) {
  unsigned u = __float_as_uint(f);
  unsigned r = 0x7fffu + ((u >> 16) & 1u);
  return (short)((u + r) >> 16);
}
__device__ __forceinline__ float bf2f(unsigned short u) {
  return __uint_as_float(((unsigned)u) << 16);
}
__device__ __forceinline__ unsigned pack2(float a, float b) {
  return (unsigned)(unsigned short)f2bf(a) | ((unsigned)(unsigned short)f2bf(b) << 16);
}

// HW packed fp32->bf16 convert: dst.lo = bf16(lo), dst.hi = bf16(hi)
__device__ __forceinline__ unsigned cvtpk_bf16(float lo, float hi) {
  unsigned r;
  asm("v_cvt_pk_bf16_f32 %0, %1, %2" : "=v"(r) : "v"(lo), "v"(hi));
  return r;
}

// 2^x via v_exp_f32
__device__ __forceinline__ float fexp2(float x) {
#if __has_builtin(__builtin_amdgcn_exp2f)
  return __builtin_amdgcn_exp2f(x);
#else
  return __expf(x * 0.69314718056f);
#endif
}

// async global->LDS, 16B per lane; LDS dest = wave-uniform base + lane*16
typedef __attribute__((address_space(1))) void GV;
typedef __attribute__((address_space(3))) void LV;
__device__ __forceinline__ void gl2lds16(const void* g, void* l) {
  __builtin_amdgcn_global_load_lds((GV*)g, (LV*)l, 16, 0, 0);
}

// bf16 relu on a packed short8 (sign-bit based; exact)
__device__ __forceinline__ short8 brelu(short8 v) {
  union { short8 s; unsigned u[4]; } x; x.s = v;
#pragma unroll
  for (int i = 0; i < 4; ++i) {
    unsigned m = (x.u[i] >> 15) & 0x10001u;
    x.u[i] &= ~(m * 0xFFFFu);
  }
  return x.s;
}

// --- key-position permutation -------------------------------------------------
// Attention computes S^T = mfma(K, Q); P stays in-lane. The PV contraction is
// invariant under k-slot permutation, so V (zT) and the bias matrix store their
// key axis permuted so P packs into A-fragments with no cross-lane moves:
//   position p(k) within each 32-key block = ((k>>2)&3)*8 + ((k>>4)&1)*4 + (k&3)
__device__ __forceinline__ int keypos(int k) {
  return (k & ~31) | (((k >> 2) & 3) << 3) | (((k >> 4) & 1) << 2);
}

// ---------------- prep: fp32->bf16 converts + iou bias (single launch) ----------------
// grid 2048 x 512. First 524288 threads convert x; first 262144 also convert the
// three weight matrices; ALL 1,048,576 threads compute 4 iou entries each and
// store iou + 1e-6 as bf16, KEY-PERMUTED.
__global__ __launch_bounds__(512) void prep_kernel(
    const float* __restrict__ in_x, const float* __restrict__ W0,
    const float* __restrict__ W1, const float* __restrict__ Wout,
    const float* __restrict__ rois,
    short* __restrict__ xin_b, short* __restrict__ W0b,
    short* __restrict__ W1b, short* __restrict__ Woutb,
    unsigned short* __restrict__ biasb)
{
  const int gi = blockIdx.x * 512 + threadIdx.x;
  if (gi < 524288) {
    const float4 v = ((const float4*)in_x)[gi];
    uint2 u; u.x = pack2(v.x, v.y); u.y = pack2(v.z, v.w);
    ((uint2*)xin_b)[gi] = u;
  }
  if (gi < 262144) {
    float4 v = ((const float4*)W0)[gi];
    uint2 u; u.x = pack2(v.x, v.y); u.y = pack2(v.z, v.w);
    ((uint2*)W0b)[gi] = u;
    v = ((const float4*)W1)[gi];
    u.x = pack2(v.x, v.y); u.y = pack2(v.z, v.w);
    ((uint2*)W1b)[gi] = u;
    v = ((const float4*)Wout)[gi];
    u.x = pack2(v.x, v.y); u.y = pack2(v.z, v.w);
    ((uint2*)Woutb)[gi] = u;
  }
  // iou + 1e-6 (linear domain, verified math)
  const int q  = gi >> 9;
  const int k0 = (gi & 511) * 4;
  const float qx1 = rois[q * 5 + 1], qy1 = rois[q * 5 + 2];
  const float qx2 = rois[q * 5 + 3], qy2 = rois[q * 5 + 4];
  const float qa = (qx2 - qx1 + 1.f) * (qy2 - qy1 + 1.f);
  float v[4];
#pragma unroll
  for (int j = 0; j < 4; ++j) {
    const int k = k0 + j;
    const float kx1 = rois[k * 5 + 1], ky1 = rois[k * 5 + 2];
    const float kx2 = rois[k * 5 + 3], ky2 = rois[k * 5 + 4];
    const float ka = (kx2 - kx1 + 1.f) * (ky2 - ky1 + 1.f);
    float iw = fminf(qx2, kx2) - fmaxf(qx1, kx1) + 1.f;
    float ih = fminf(qy2, ky2) - fmaxf(qy1, ky1) + 1.f;
    iw = fmaxf(iw, 0.f); ih = fmaxf(ih, 0.f);
    const float inter = iw * ih;
    v[j] = inter * __builtin_amdgcn_rcpf(qa + ka - inter) + 1e-6f;
  }
  uint2 u; u.x = pack2(v[0], v[1]); u.y = pack2(v[2], v[3]);
  *(uint2*)&biasb[(size_t)q * NROI + keypos(k0)] = u;
}

// ---------------- 64x64 double-buffered GEMM, high occupancy (R5/R7-verified) ----------------
// FUSED=1: blockIdx.x<16 -> t0 = relu(x)@W0^T+b0 (row-major); else
//          zT = (x@Wout^T)^T (transposed out, KEY-PERMUTED rows). grid (32,32).
// FUSED=0: C = relu(A)@B^T + bias (row-major). grid (16,32).
template <int FUSED>
__global__ __launch_bounds__(256, 4) void gemm64(
    const short* __restrict__ A, const short* __restrict__ Ba,
    const short* __restrict__ Bb, const float* __restrict__ bias,
    short* __restrict__ outRM, short* __restrict__ outTR)
{
  __shared__ short As[2][8 * 512];
  __shared__ short Bs[2][8 * 512];
  const int t = threadIdx.x, w = t >> 6, lane = t & 63;
  const int wm = w >> 1, wn = w & 1;
  const int row0 = blockIdx.y * 64;
  bool isW0; int col0; const short* B;
  if (FUSED) {
    isW0 = blockIdx.x < 16;
    col0 = (blockIdx.x & 15) * 64;
    B = isW0 ? Ba : Bb;
  } else {
    isW0 = true; col0 = blockIdx.x * 64; B = Ba;
  }
  const bool doRelu = FUSED ? isW0 : true;
  const int rlo = lane & 15, khi = (lane >> 4) * 8;

  floatx4 acc[2][2];
#pragma unroll
  for (int i = 0; i < 2; ++i)
#pragma unroll
    for (int j = 0; j < 2; ++j) acc[i][j] = (floatx4){0.f, 0.f, 0.f, 0.f};

#pragma unroll
  for (int kh = 0; kh < 2; ++kh) {
    const int f = w * 2 + kh;
    gl2lds16(A + (size_t)(row0 + w * 16 + rlo) * CDIM + kh * 32 + khi, &As[0][f * 512]);
    gl2lds16(B + (size_t)(col0 + w * 16 + rlo) * CDIM + kh * 32 + khi, &Bs[0][f * 512]);
  }
  __syncthreads();

  for (int it = 0; it < 16; ++it) {
    const int p = it & 1;
    if (it < 15) {
      const int k1 = (it + 1) * 64;
#pragma unroll
      for (int kh = 0; kh < 2; ++kh) {
        const int f = w * 2 + kh;
        gl2lds16(A + (size_t)(row0 + w * 16 + rlo) * CDIM + k1 + kh * 32 + khi,
                 &As[1 - p][f * 512]);
        gl2lds16(B + (size_t)(col0 + w * 16 + rlo) * CDIM + k1 + kh * 32 + khi,
                 &Bs[1 - p][f * 512]);
      }
    }
#pragma unroll
    for (int kh = 0; kh < 2; ++kh) {
      short8 a[2], bf[2];
#pragma unroll
      for (int i = 0; i < 2; ++i) {
        a[i] = *(const short8*)&As[p][((wm * 2 + i) * 2 + kh) * 512 + lane * 8];
        if (doRelu) a[i] = brelu(a[i]);
      }
#pragma unroll
      for (int j = 0; j < 2; ++j)
        bf[j] = *(const short8*)&Bs[p][((wn * 2 + j) * 2 + kh) * 512 + lane * 8];
#pragma unroll
      for (int i = 0; i < 2; ++i)
#pragma unroll
        for (int j = 0; j < 2; ++j)
          acc[i][j] = MFMA_BF16(a[i], bf[j], acc[i][j]);
    }
    __syncthreads();
  }

  const int colL = lane & 15, qq = lane >> 4;
  if (!FUSED || isW0) {
    float bj[2];
    bj[0] = bias[col0 + wn * 32 + colL];
    bj[1] = bias[col0 + wn * 32 + 16 + colL];
#pragma unroll
    for (int i = 0; i < 2; ++i)
#pragma unroll
      for (int j = 0; j < 2; ++j)
#pragma unroll
        for (int r = 0; r < 4; ++r) {
          const int row = row0 + wm * 32 + i * 16 + qq * 4 + r;
          const int cc  = col0 + wn * 32 + j * 16 + colL;
          outRM[(size_t)row * CDIM + cc] = f2bf(acc[i][j][r] + bj[j]);
        }
  } else {
#pragma unroll
    for (int i = 0; i < 2; ++i)
#pragma unroll
      for (int j = 0; j < 2; ++j) {
        unsigned long long u =
            (unsigned long long)pack2(acc[i][j][0], acc[i][j][1]) |
            ((unsigned long long)pack2(acc[i][j][2], acc[i][j][3]) << 32);
        const int cc  = col0 + wn * 32 + j * 16 + colL;
        const int row = row0 + wm * 32 + i * 16 + qq * 4;   // 4-aligned key group
        *(unsigned long long*)&outTR[(size_t)cc * NROI + keypos(row)] = u;
      }
  }
}

// ---------------- MFMA flash attention, v8 ----------------
// v6 skeleton (R7-verified: 16 waves = 4 key-quarters x 4 q-waves, 32 q/wave,
// 8 iters, double-buffered K/V staging, ones-MFMA denominator) + ONE isolated
// change: the bias loads are double-buffered in registers (BU/BUn, +16 VGPR),
// so their L3-class latency (8MB bias working set > 4MB XCD L2) is hidden a
// full iteration ahead instead of sitting on the QK->pv critical path.
// No sync-structure, indexing, or fragment-math changes (R8's z[2][4]
// restructure -- the spill cause -- is NOT included).
__global__ __launch_bounds__(1024) void attn_bias(
    const short* __restrict__ Xb,             // (N,C) bf16 embedded x
    const short* __restrict__ ZTb,            // (C,N) bf16 V, transposed, key-permuted
    const unsigned short* __restrict__ biasb, // (N,N) bf16 iou+1e-6, key-permuted
    const float* __restrict__ bout,
    float* __restrict__ Out)
{
  // XCD-aware decode: lin%8 = XCD. XCD x hosts groups {2x, 2x+1}.
  const int lin  = blockIdx.x + 16 * blockIdx.y;   // 256 blocks
  const int xcd  = lin & 7;
  const int slot = lin >> 3;                       // 0..31
  const int g    = 2 * xcd + (slot >> 4);
  const int n0   = (slot & 15) * 128;

  const int t    = threadIdx.x;
  const int w    = t >> 6;
  const int qt   = w >> 2;      // key quarter 0..3 -> keys [qt*512, qt*512+512)
  const int wq   = w & 3;       // q-pair index: q rows [n0+wq*32, n0+wq*32+32)
  const int lane = t & 63;
  const int col  = lane & 15;
  const int qq   = lane >> 4;
  const int rlo  = col, khi = qq * 8;

  __shared__ short Kq[4][2][4096];  // [quarter][buf][8 frags x 512]
  __shared__ short Vq[4][2][4096];

  // Q fragments for the two 16-q subtiles
  short8 qf[2][2];
#pragma unroll
  for (int s = 0; s < 2; ++s) {
    const size_t qoff = (size_t)(n0 + wq * 32 + s * 16 + col) * CDIM + g * DH;
    qf[s][0] = *(const short8*)(Xb + qoff + qq * 8);
    qf[s][1] = *(const short8*)(Xb + qoff + 32 + qq * 8);
  }

  // constant ones B-fragment (bf16 1.0) for the denominator MFMA
  short8 ONES;
#pragma unroll
  for (int i = 0; i < 8; ++i) ONES[i] = (short)0x3F80;

  floatx4 oc[2][4];   // [sub][dt]
#pragma unroll
  for (int s = 0; s < 2; ++s)
#pragma unroll
    for (int dt = 0; dt < 4; ++dt) oc[s][dt] = (floatx4){0.f, 0.f, 0.f, 0.f};
  floatx4 lsA[2];     // denominator, same (qq,r) layout as oc rows
  lsA[0] = (floatx4){0.f, 0.f, 0.f, 0.f};
  lsA[1] = (floatx4){0.f, 0.f, 0.f, 0.f};

  const int kb = qt * 512;   // this quarter's key base

  // stage iter 0: wave wq stages key-subtile wq (both k/key halves)
#pragma unroll
  for (int kh = 0; kh < 2; ++kh) {
    gl2lds16(Xb + (size_t)(kb + wq * 16 + rlo) * CDIM + g * DH + kh * 32 + khi,
             &Kq[qt][0][(wq * 2 + kh) * 512]);
    gl2lds16(ZTb + (size_t)(g * DH + wq * 16 + rlo) * NROI + kb + kh * 32 + khi,
             &Vq[qt][0][(wq * 2 + kh) * 512]);
  }
  __syncthreads();

  const unsigned short* bq0 =
      biasb + (size_t)(n0 + wq * 32 + col) * NROI + kb + qq * 8;
  const unsigned short* bq1 = bq0 + (size_t)16 * NROI;

  // bias double-buffer: BU = current iter, BUn = next iter (prefetched)
  union BUu { short8 s8[4]; unsigned short h[32]; };
  BUu BU, BUn;
  BU.s8[0] = *(const short8*)(bq0);
  BU.s8[1] = *(const short8*)(bq0 + 32);
  BU.s8[2] = *(const short8*)(bq1);
  BU.s8[3] = *(const short8*)(bq1 + 32);

  for (int it = 0; it < 8; ++it) {
    const int p  = it & 1;
    const int m0 = kb + it * 64;

    if (it + 1 < 8) {
      // prefetch next iteration's bias (consumed a full iteration later)
      BUn.s8[0] = *(const short8*)(bq0 + (it + 1) * 64);
      BUn.s8[1] = *(const short8*)(bq0 + (it + 1) * 64 + 32);
      BUn.s8[2] = *(const short8*)(bq1 + (it + 1) * 64);
      BUn.s8[3] = *(const short8*)(bq1 + (it + 1) * 64 + 32);
      // K/V staging prefetch for next iteration
      const int m1 = m0 + 64;
#pragma unroll
      for (int kh = 0; kh < 2; ++kh) {
        gl2lds16(Xb + (size_t)(m1 + wq * 16 + rlo) * CDIM + g * DH + kh * 32 + khi,
                 &Kq[qt][1 - p][(wq * 2 + kh) * 512]);
        gl2lds16(ZTb + (size_t)(g * DH + wq * 16 + rlo) * NROI + m1 + kh * 32 + khi,
                 &Vq[qt][1 - p][(wq * 2 + kh) * 512]);
      }
    }

    // QK + softmax-weight + pack, per 16-key column-tile ct; each K-frag pair
    // feeds BOTH q-subtiles (the LDS-read amortization).
    union { short8 s; unsigned u[4]; } U[2][2];   // [sub][kslot-half]
#pragma unroll
    for (int ct = 0; ct < 4; ++ct) {
      const short8 k0 = *(const short8*)&Kq[qt][p][(ct * 2 + 0) * 512 + lane * 8];
      const short8 k1 = *(const short8*)&Kq[qt][p][(ct * 2 + 1) * 512 + lane * 8];
#pragma unroll
      for (int s = 0; s < 2; ++s) {
        floatx4 z4 = (floatx4){0.f, 0.f, 0.f, 0.f};
        z4 = MFMA_BF16(k0, qf[s][0], z4);
        z4 = MFMA_BF16(k1, qf[s][1], z4);
        float pv0 = fexp2(z4[0] * 0.18033688011f) * bf2f(BU.h[s * 16 + ct * 4 + 0]);
        float pv1 = fexp2(z4[1] * 0.18033688011f) * bf2f(BU.h[s * 16 + ct * 4 + 1]);
        float pv2 = fexp2(z4[2] * 0.18033688011f) * bf2f(BU.h[s * 16 + ct * 4 + 2]);
        float pv3 = fexp2(z4[3] * 0.18033688011f) * bf2f(BU.h[s * 16 + ct * 4 + 3]);
        U[s][ct >> 1].u[(ct & 1) * 2 + 0] = cvtpk_bf16(pv0, pv1);
        U[s][ct >> 1].u[(ct & 1) * 2 + 1] = cvtpk_bf16(pv2, pv3);
      }
    }

    // denominator: rowsum of packed P via ones-column MFMA (static indices)
    lsA[0] = MFMA_BF16(U[0][0].s, ONES, lsA[0]);
    lsA[0] = MFMA_BF16(U[0][1].s, ONES, lsA[0]);
    lsA[1] = MFMA_BF16(U[1][0].s, ONES, lsA[1]);
    lsA[1] = MFMA_BF16(U[1][1].s, ONES, lsA[1]);

    // PV: each V-frag pair feeds both q-subtiles
#pragma unroll
    for (int dt = 0; dt < 4; ++dt) {
      const short8 v0 = *(const short8*)&Vq[qt][p][(dt * 2 + 0) * 512 + lane * 8];
      const short8 v1 = *(const short8*)&Vq[qt][p][(dt * 2 + 1) * 512 + lane * 8];
#pragma unroll
      for (int s = 0; s < 2; ++s) {
        oc[s][dt] = MFMA_BF16(U[s][0].s, v0, oc[s][dt]);
        oc[s][dt] = MFMA_BF16(U[s][1].s, v1, oc[s][dt]);
      }
    }

    // rotate bias pipeline (register copy)
    BU = BUn;
    __syncthreads();
  }

  // cross-quarter combine via LDS (K/V buffers dead). oc: lane-contiguous
  // [elem][wave12][lane] (conflict-free). lsA[s][r] is identical across the 16
  // lanes of a qq-group, so col==0 lanes store 32 floats per wave; readers hit
  // the same address per qq-group -> LDS broadcast.
  float* kbuf = (float*)&Kq[0][0][0];   // 16384 floats
  float* vbuf = (float*)&Vq[0][0][0];   // 16384 floats
  const int wslot = (qt - 1) * 4 + wq;  // 0..11 for quarters 1..3
  if (qt != 0) {
#pragma unroll
    for (int dt = 0; dt < 4; ++dt)
#pragma unroll
      for (int r = 0; r < 4; ++r) {
        kbuf[(dt * 4 + r) * 768 + wslot * 64 + lane] = oc[0][dt][r];
        vbuf[(dt * 4 + r) * 768 + wslot * 64 + lane] = oc[1][dt][r];
      }
    if (col == 0) {
#pragma unroll
      for (int s = 0; s < 2; ++s)
#pragma unroll
        for (int r = 0; r < 4; ++r)
          kbuf[12288 + wslot * 32 + s * 16 + qq * 4 + r] = lsA[s][r];
    }
  }
  __syncthreads();
  if (qt == 0) {
    float ls[2][4];
#pragma unroll
    for (int s = 0; s < 2; ++s)
#pragma unroll
      for (int r = 0; r < 4; ++r) ls[s][r] = lsA[s][r];
#pragma unroll
    for (int j = 0; j < 3; ++j) {
      const int ws = j * 4 + wq;
#pragma unroll
      for (int dt = 0; dt < 4; ++dt)
#pragma unroll
        for (int r = 0; r < 4; ++r) {
          oc[0][dt][r] += kbuf[(dt * 4 + r) * 768 + ws * 64 + lane];
          oc[1][dt][r] += vbuf[(dt * 4 + r) * 768 + ws * 64 + lane];
        }
#pragma unroll
      for (int s = 0; s < 2; ++s)
#pragma unroll
        for (int r = 0; r < 4; ++r)
          ls[s][r] += kbuf[12288 + ws * 32 + s * 16 + qq * 4 + r];
    }
#pragma unroll
    for (int s = 0; s < 2; ++s) {
      float rinv[4];
#pragma unroll
      for (int r = 0; r < 4; ++r)
        rinv[r] = __builtin_amdgcn_rcpf(ls[s][r]);
#pragma unroll
      for (int dt = 0; dt < 4; ++dt) {
        const float bo = bout[g * DH + dt * 16 + col];
#pragma unroll
        for (int r = 0; r < 4; ++r)
          Out[(size_t)(n0 + wq * 32 + s * 16 + qq * 4 + r) * CDIM + g * DH +
              dt * 16 + col] = oc[s][dt][r] * rinv[r] + bo;
      }
    }
  }
}

extern "C" void kernel_launch(void* const* d_in, const int* in_sizes, int n_in,
                              void* d_out, int out_size, void* d_ws, size_t ws_size,
                              hipStream_t stream) {
  const float* in_x = (const float*)d_in[0];
  const float* rois = (const float*)d_in[1];
  const float* W0   = (const float*)d_in[2];
  const float* b0   = (const float*)d_in[3];
  const float* W1   = (const float*)d_in[4];
  const float* b1   = (const float*)d_in[5];
  const float* Wout = (const float*)d_in[6];  // (G,D,C) flat == (C,C) row-major
  const float* bout = (const float*)d_in[7];
  char* w8 = (char*)d_ws;

  // ws layout (22 MB):
  //   [0,4M)   xin_b (bf16 x) -> xb (gemm1 out; xin_b dead after gemm64<1>)
  //   [4,6M)   W0b   [6,8M) W1b   [8,10M) Woutb
  //   [10,14M) zT (bf16 V^T, key-permuted)
  //   [14,22M) biasb (bf16 iou+1e-6, key-permuted)
  short* xin_b = (short*)w8;
  short* W0b   = (short*)(w8 + ((size_t)4 << 20));
  short* W1b   = (short*)(w8 + ((size_t)6 << 20));
  short* Woutb = (short*)(w8 + ((size_t)8 << 20));
  short* zT    = (short*)(w8 + ((size_t)10 << 20));
  unsigned short* biasb = (unsigned short*)(w8 + ((size_t)14 << 20));
  short* xb  = xin_b;
  short* t0b = (short*)d_out;

  // 1) merged converts + iou bias (one launch)
  prep_kernel<<<2048, 512, 0, stream>>>(in_x, W0, W1, Wout, rois,
                                        xin_b, W0b, W1b, Woutb, biasb);
  // 2) fused 64x64 high-occupancy: t0 = relu(x)@W0^T+b0 and zT = (x@Wout^T)^T
  gemm64<1><<<dim3(32, 32), 256, 0, stream>>>(xin_b, W0b, Woutb, b0, t0b, zT);
  // 3) 64x64 high-occupancy: xb = relu(t0)@W1^T + b1
  gemm64<0><<<dim3(16, 32), 256, 0, stream>>>(t0b, W1b, nullptr, b1, xb, nullptr);
  // 4) flash attention v8 (v6 + bias register double-buffer ONLY)
  attn_bias<<<dim3(16, 16), 1024, 0, stream>>>(xb, zT, biasb, bout,
                                               (float*)d_out);
}

// Round 12
// 180.641 us; speedup vs baseline: 1.1478x; 1.0010x over previous
//
#include <hip/hip_runtime.h>
#include <math.h>

// Problem constants
constexpr int NROI = 2048;  // N
constexpr int CDIM = 1024;  // C
constexpr int NG   = 16;    // groups
constexpr int DH   = 64;    // per-group dim

typedef __attribute__((ext_vector_type(8))) short short8;    // 8 bf16 (4 VGPRs)
typedef __attribute__((ext_vector_type(4))) float floatx4;   // MFMA C/D frag

#define MFMA_BF16(a, b, c) __builtin_amdgcn_mfma_f32_16x16x32_bf16((a), (b), (c), 0, 0, 0)

// fp32 -> bf16 round-to-nearest-even
__device__ __forceinline__ short f2bf(float f) {
  unsigned u = __float_as_uint(f);
  unsigned r = 0x7fffu + ((u >> 16) & 1u);
  return (short)((u + r) >> 16);
}
__device__ __forceinline__ float bf2f(unsigned short u) {
  return __uint_as_float(((unsigned)u) << 16);
}
__device__ __forceinline__ unsigned pack2(float a, float b) {
  return (unsigned)(unsigned short)f2bf(a) | ((unsigned)(unsigned short)f2bf(b) << 16);
}

// HW packed fp32->bf16 convert: dst.lo = bf16(lo), dst.hi = bf16(hi)
__device__ __forceinline__ unsigned cvtpk_bf16(float lo, float hi) {
  unsigned r;
  asm("v_cvt_pk_bf16_f32 %0, %1, %2" : "=v"(r) : "v"(lo), "v"(hi));
  return r;
}

// 2^x via v_exp_f32
__device__ __forceinline__ float fexp2(float x) {
#if __has_builtin(__builtin_amdgcn_exp2f)
  return __builtin_amdgcn_exp2f(x);
#else
  return __expf(x * 0.69314718056f);
#endif
}

// async global->LDS, 16B per lane; LDS dest = wave-uniform base + lane*16
typedef __attribute__((address_space(1))) void GV;
typedef __attribute__((address_space(3))) void LV;
__device__ __forceinline__ void gl2lds16(const void* g, void* l) {
  __builtin_amdgcn_global_load_lds((GV*)g, (LV*)l, 16, 0, 0);
}

// bf16 relu on a packed short8 (sign-bit based; exact)
__device__ __forceinline__ short8 brelu(short8 v) {
  union { short8 s; unsigned u[4]; } x; x.s = v;
#pragma unroll
  for (int i = 0; i < 4; ++i) {
    unsigned m = (x.u[i] >> 15) & 0x10001u;
    x.u[i] &= ~(m * 0xFFFFu);
  }
  return x.s;
}

// --- key-position permutation -------------------------------------------------
// Attention computes S^T = mfma(K, Q); P stays in-lane. The PV contraction is
// invariant under k-slot permutation, so V (zT) and the bias matrix store their
// key axis permuted so P packs into A-fragments with no cross-lane moves:
//   position p(k) within each 32-key block = ((k>>2)&3)*8 + ((k>>4)&1)*4 + (k&3)
__device__ __forceinline__ int keypos(int k) {
  return (k & ~31) | (((k >> 2) & 3) << 3) | (((k >> 4) & 1) << 2);
}

// ---------------- prep: fp32->bf16 converts + iou bias (single launch) ----------------
// grid 2048 x 512. First 524288 threads convert x; first 262144 also convert the
// three weight matrices; ALL 1,048,576 threads compute 4 iou entries each and
// store iou + 1e-6 as bf16, KEY-PERMUTED.
__global__ __launch_bounds__(512) void prep_kernel(
    const float* __restrict__ in_x, const float* __restrict__ W0,
    const float* __restrict__ W1, const float* __restrict__ Wout,
    const float* __restrict__ rois,
    short* __restrict__ xin_b, short* __restrict__ W0b,
    short* __restrict__ W1b, short* __restrict__ Woutb,
    unsigned short* __restrict__ biasb)
{
  const int gi = blockIdx.x * 512 + threadIdx.x;
  if (gi < 524288) {
    const float4 v = ((const float4*)in_x)[gi];
    uint2 u; u.x = pack2(v.x, v.y); u.y = pack2(v.z, v.w);
    ((uint2*)xin_b)[gi] = u;
  }
  if (gi < 262144) {
    float4 v = ((const float4*)W0)[gi];
    uint2 u; u.x = pack2(v.x, v.y); u.y = pack2(v.z, v.w);
    ((uint2*)W0b)[gi] = u;
    v = ((const float4*)W1)[gi];
    u.x = pack2(v.x, v.y); u.y = pack2(v.z, v.w);
    ((uint2*)W1b)[gi] = u;
    v = ((const float4*)Wout)[gi];
    u.x = pack2(v.x, v.y); u.y = pack2(v.z, v.w);
    ((uint2*)Woutb)[gi] = u;
  }
  // iou + 1e-6 (linear domain, verified math)
  const int q  = gi >> 9;
  const int k0 = (gi & 511) * 4;
  const float qx1 = rois[q * 5 + 1], qy1 = rois[q * 5 + 2];
  const float qx2 = rois[q * 5 + 3], qy2 = rois[q * 5 + 4];
  const float qa = (qx2 - qx1 + 1.f) * (qy2 - qy1 + 1.f);
  float v[4];
#pragma unroll
  for (int j = 0; j < 4; ++j) {
    const int k = k0 + j;
    const float kx1 = rois[k * 5 + 1], ky1 = rois[k * 5 + 2];
    const float kx2 = rois[k * 5 + 3], ky2 = rois[k * 5 + 4];
    const float ka = (kx2 - kx1 + 1.f) * (ky2 - ky1 + 1.f);
    float iw = fminf(qx2, kx2) - fmaxf(qx1, kx1) + 1.f;
    float ih = fminf(qy2, ky2) - fmaxf(qy1, ky1) + 1.f;
    iw = fmaxf(iw, 0.f); ih = fmaxf(ih, 0.f);
    const float inter = iw * ih;
    v[j] = inter * __builtin_amdgcn_rcpf(qa + ka - inter) + 1e-6f;
  }
  uint2 u; u.x = pack2(v[0], v[1]); u.y = pack2(v[2], v[3]);
  *(uint2*)&biasb[(size_t)q * NROI + keypos(k0)] = u;
}

// ---------------- 64x64 double-buffered GEMM, high occupancy (R5/R7-verified) ----------------
// + XCD-aware bijective block swizzle (T1): 8 consecutive lin-chunks pinned per
// XCD so A row-panels and B col-panels become L2-resident. Pure blockIdx
// permutation (grid sizes divisible by 8 -> bijective); zero correctness surface.
// FUSED=1: bx<16 -> t0 = relu(x)@W0^T+b0 (row-major); else
//          zT = (x@Wout^T)^T (transposed out, KEY-PERMUTED rows). grid (32,32).
// FUSED=0: C = relu(A)@B^T + bias (row-major). grid (16,32).
template <int FUSED>
__global__ __launch_bounds__(256, 4) void gemm64(
    const short* __restrict__ A, const short* __restrict__ Ba,
    const short* __restrict__ Bb, const float* __restrict__ bias,
    short* __restrict__ outRM, short* __restrict__ outTR)
{
  __shared__ short As[2][8 * 512];
  __shared__ short Bs[2][8 * 512];
  const int t = threadIdx.x, w = t >> 6, lane = t & 63;
  const int wm = w >> 1, wn = w & 1;

  // XCD swizzle: lin0 % 8 = XCD (HW round-robin); give each XCD a contiguous
  // chunk of cpx tiles. nwg divisible by 8 -> bijective.
  const int nwgx = FUSED ? 32 : 16;
  const int nwg  = nwgx * 32;
  const int cpx  = nwg >> 3;
  const int lin0 = blockIdx.y * nwgx + blockIdx.x;
  const int lin  = (lin0 & 7) * cpx + (lin0 >> 3);
  const int bx   = lin % nwgx;
  const int by   = lin / nwgx;

  const int row0 = by * 64;
  bool isW0; int col0; const short* B;
  if (FUSED) {
    isW0 = bx < 16;
    col0 = (bx & 15) * 64;
    B = isW0 ? Ba : Bb;
  } else {
    isW0 = true; col0 = bx * 64; B = Ba;
  }
  const bool doRelu = FUSED ? isW0 : true;
  const int rlo = lane & 15, khi = (lane >> 4) * 8;

  floatx4 acc[2][2];
#pragma unroll
  for (int i = 0; i < 2; ++i)
#pragma unroll
    for (int j = 0; j < 2; ++j) acc[i][j] = (floatx4){0.f, 0.f, 0.f, 0.f};

#pragma unroll
  for (int kh = 0; kh < 2; ++kh) {
    const int f = w * 2 + kh;
    gl2lds16(A + (size_t)(row0 + w * 16 + rlo) * CDIM + kh * 32 + khi, &As[0][f * 512]);
    gl2lds16(B + (size_t)(col0 + w * 16 + rlo) * CDIM + kh * 32 + khi, &Bs[0][f * 512]);
  }
  __syncthreads();

  for (int it = 0; it < 16; ++it) {
    const int p = it & 1;
    if (it < 15) {
      const int k1 = (it + 1) * 64;
#pragma unroll
      for (int kh = 0; kh < 2; ++kh) {
        const int f = w * 2 + kh;
        gl2lds16(A + (size_t)(row0 + w * 16 + rlo) * CDIM + k1 + kh * 32 + khi,
                 &As[1 - p][f * 512]);
        gl2lds16(B + (size_t)(col0 + w * 16 + rlo) * CDIM + k1 + kh * 32 + khi,
                 &Bs[1 - p][f * 512]);
      }
    }
#pragma unroll
    for (int kh = 0; kh < 2; ++kh) {
      short8 a[2], bf[2];
#pragma unroll
      for (int i = 0; i < 2; ++i) {
        a[i] = *(const short8*)&As[p][((wm * 2 + i) * 2 + kh) * 512 + lane * 8];
        if (doRelu) a[i] = brelu(a[i]);
      }
#pragma unroll
      for (int j = 0; j < 2; ++j)
        bf[j] = *(const short8*)&Bs[p][((wn * 2 + j) * 2 + kh) * 512 + lane * 8];
#pragma unroll
      for (int i = 0; i < 2; ++i)
#pragma unroll
        for (int j = 0; j < 2; ++j)
          acc[i][j] = MFMA_BF16(a[i], bf[j], acc[i][j]);
    }
    __syncthreads();
  }

  const int colL = lane & 15, qq = lane >> 4;
  if (!FUSED || isW0) {
    float bj[2];
    bj[0] = bias[col0 + wn * 32 + colL];
    bj[1] = bias[col0 + wn * 32 + 16 + colL];
#pragma unroll
    for (int i = 0; i < 2; ++i)
#pragma unroll
      for (int j = 0; j < 2; ++j)
#pragma unroll
        for (int r = 0; r < 4; ++r) {
          const int row = row0 + wm * 32 + i * 16 + qq * 4 + r;
          const int cc  = col0 + wn * 32 + j * 16 + colL;
          outRM[(size_t)row * CDIM + cc] = f2bf(acc[i][j][r] + bj[j]);
        }
  } else {
#pragma unroll
    for (int i = 0; i < 2; ++i)
#pragma unroll
      for (int j = 0; j < 2; ++j) {
        unsigned long long u =
            (unsigned long long)pack2(acc[i][j][0], acc[i][j][1]) |
            ((unsigned long long)pack2(acc[i][j][2], acc[i][j][3]) << 32);
        const int cc  = col0 + wn * 32 + j * 16 + colL;
        const int row = row0 + wm * 32 + i * 16 + qq * 4;   // 4-aligned key group
        *(unsigned long long*)&outTR[(size_t)cc * NROI + keypos(row)] = u;
      }
  }
}

// ---------------- MFMA flash attention, v6 (R7-verified champion, verbatim) ----------------
// 16 waves = 4 key-quarters x 4 q-waves, 32 q/wave, 8 iters, double-buffered
// K/V staging; softmax denominator via ones-column MFMA (lands in oc layout).
__global__ __launch_bounds__(1024) void attn_bias(
    const short* __restrict__ Xb,             // (N,C) bf16 embedded x
    const short* __restrict__ ZTb,            // (C,N) bf16 V, transposed, key-permuted
    const unsigned short* __restrict__ biasb, // (N,N) bf16 iou+1e-6, key-permuted
    const float* __restrict__ bout,
    float* __restrict__ Out)
{
  // XCD-aware decode: lin%8 = XCD. XCD x hosts groups {2x, 2x+1}.
  const int lin  = blockIdx.x + 16 * blockIdx.y;   // 256 blocks
  const int xcd  = lin & 7;
  const int slot = lin >> 3;                       // 0..31
  const int g    = 2 * xcd + (slot >> 4);
  const int n0   = (slot & 15) * 128;

  const int t    = threadIdx.x;
  const int w    = t >> 6;
  const int qt   = w >> 2;      // key quarter 0..3 -> keys [qt*512, qt*512+512)
  const int wq   = w & 3;       // q-pair index: q rows [n0+wq*32, n0+wq*32+32)
  const int lane = t & 63;
  const int col  = lane & 15;
  const int qq   = lane >> 4;
  const int rlo  = col, khi = qq * 8;

  __shared__ short Kq[4][2][4096];  // [quarter][buf][8 frags x 512]
  __shared__ short Vq[4][2][4096];

  // Q fragments for the two 16-q subtiles
  short8 qf[2][2];
#pragma unroll
  for (int s = 0; s < 2; ++s) {
    const size_t qoff = (size_t)(n0 + wq * 32 + s * 16 + col) * CDIM + g * DH;
    qf[s][0] = *(const short8*)(Xb + qoff + qq * 8);
    qf[s][1] = *(const short8*)(Xb + qoff + 32 + qq * 8);
  }

  // constant ones B-fragment (bf16 1.0) for the denominator MFMA
  short8 ONES;
#pragma unroll
  for (int i = 0; i < 8; ++i) ONES[i] = (short)0x3F80;

  floatx4 oc[2][4];   // [sub][dt]
#pragma unroll
  for (int s = 0; s < 2; ++s)
#pragma unroll
    for (int dt = 0; dt < 4; ++dt) oc[s][dt] = (floatx4){0.f, 0.f, 0.f, 0.f};
  floatx4 lsA[2];     // denominator, same (qq,r) layout as oc rows
  lsA[0] = (floatx4){0.f, 0.f, 0.f, 0.f};
  lsA[1] = (floatx4){0.f, 0.f, 0.f, 0.f};

  const int kb = qt * 512;   // this quarter's key base

  // stage iter 0: wave wq stages key-subtile wq (both k/key halves)
#pragma unroll
  for (int kh = 0; kh < 2; ++kh) {
    gl2lds16(Xb + (size_t)(kb + wq * 16 + rlo) * CDIM + g * DH + kh * 32 + khi,
             &Kq[qt][0][(wq * 2 + kh) * 512]);
    gl2lds16(ZTb + (size_t)(g * DH + wq * 16 + rlo) * NROI + kb + kh * 32 + khi,
             &Vq[qt][0][(wq * 2 + kh) * 512]);
  }
  __syncthreads();

  const unsigned short* bq0 =
      biasb + (size_t)(n0 + wq * 32 + col) * NROI + kb + qq * 8;
  const unsigned short* bq1 = bq0 + (size_t)16 * NROI;

  for (int it = 0; it < 8; ++it) {
    const int p  = it & 1;
    const int m0 = kb + it * 64;

    // bias: four coalesced 16B loads (two per q-subtile), issued early
    union { short8 s8[4]; unsigned short h[32]; } BU;
    BU.s8[0] = *(const short8*)(bq0 + it * 64);
    BU.s8[1] = *(const short8*)(bq0 + it * 64 + 32);
    BU.s8[2] = *(const short8*)(bq1 + it * 64);
    BU.s8[3] = *(const short8*)(bq1 + it * 64 + 32);

    if (it + 1 < 8) {
      const int m1 = m0 + 64;
#pragma unroll
      for (int kh = 0; kh < 2; ++kh) {
        gl2lds16(Xb + (size_t)(m1 + wq * 16 + rlo) * CDIM + g * DH + kh * 32 + khi,
                 &Kq[qt][1 - p][(wq * 2 + kh) * 512]);
        gl2lds16(ZTb + (size_t)(g * DH + wq * 16 + rlo) * NROI + m1 + kh * 32 + khi,
                 &Vq[qt][1 - p][(wq * 2 + kh) * 512]);
      }
    }

    // QK + softmax-weight + pack, per 16-key column-tile ct; each K-frag pair
    // feeds BOTH q-subtiles (the LDS-read amortization).
    union { short8 s; unsigned u[4]; } U[2][2];   // [sub][kslot-half]
#pragma unroll
    for (int ct = 0; ct < 4; ++ct) {
      const short8 k0 = *(const short8*)&Kq[qt][p][(ct * 2 + 0) * 512 + lane * 8];
      const short8 k1 = *(const short8*)&Kq[qt][p][(ct * 2 + 1) * 512 + lane * 8];
#pragma unroll
      for (int s = 0; s < 2; ++s) {
        floatx4 z4 = (floatx4){0.f, 0.f, 0.f, 0.f};
        z4 = MFMA_BF16(k0, qf[s][0], z4);
        z4 = MFMA_BF16(k1, qf[s][1], z4);
        float pv0 = fexp2(z4[0] * 0.18033688011f) * bf2f(BU.h[s * 16 + ct * 4 + 0]);
        float pv1 = fexp2(z4[1] * 0.18033688011f) * bf2f(BU.h[s * 16 + ct * 4 + 1]);
        float pv2 = fexp2(z4[2] * 0.18033688011f) * bf2f(BU.h[s * 16 + ct * 4 + 2]);
        float pv3 = fexp2(z4[3] * 0.18033688011f) * bf2f(BU.h[s * 16 + ct * 4 + 3]);
        U[s][ct >> 1].u[(ct & 1) * 2 + 0] = cvtpk_bf16(pv0, pv1);
        U[s][ct >> 1].u[(ct & 1) * 2 + 1] = cvtpk_bf16(pv2, pv3);
      }
    }

    // denominator: rowsum of packed P via ones-column MFMA (static indices)
    lsA[0] = MFMA_BF16(U[0][0].s, ONES, lsA[0]);
    lsA[0] = MFMA_BF16(U[0][1].s, ONES, lsA[0]);
    lsA[1] = MFMA_BF16(U[1][0].s, ONES, lsA[1]);
    lsA[1] = MFMA_BF16(U[1][1].s, ONES, lsA[1]);

    // PV: each V-frag pair feeds both q-subtiles
#pragma unroll
    for (int dt = 0; dt < 4; ++dt) {
      const short8 v0 = *(const short8*)&Vq[qt][p][(dt * 2 + 0) * 512 + lane * 8];
      const short8 v1 = *(const short8*)&Vq[qt][p][(dt * 2 + 1) * 512 + lane * 8];
#pragma unroll
      for (int s = 0; s < 2; ++s) {
        oc[s][dt] = MFMA_BF16(U[s][0].s, v0, oc[s][dt]);
        oc[s][dt] = MFMA_BF16(U[s][1].s, v1, oc[s][dt]);
      }
    }
    __syncthreads();
  }

  // cross-quarter combine via LDS (K/V buffers dead). oc: lane-contiguous
  // [elem][wave12][lane] (conflict-free). lsA[s][r] is identical across the 16
  // lanes of a qq-group, so col==0 lanes store 32 floats per wave; readers hit
  // the same address per qq-group -> LDS broadcast.
  float* kbuf = (float*)&Kq[0][0][0];   // 16384 floats
  float* vbuf = (float*)&Vq[0][0][0];   // 16384 floats
  const int wslot = (qt - 1) * 4 + wq;  // 0..11 for quarters 1..3
  if (qt != 0) {
#pragma unroll
    for (int dt = 0; dt < 4; ++dt)
#pragma unroll
      for (int r = 0; r < 4; ++r) {
        kbuf[(dt * 4 + r) * 768 + wslot * 64 + lane] = oc[0][dt][r];
        vbuf[(dt * 4 + r) * 768 + wslot * 64 + lane] = oc[1][dt][r];
      }
    if (col == 0) {
#pragma unroll
      for (int s = 0; s < 2; ++s)
#pragma unroll
        for (int r = 0; r < 4; ++r)
          kbuf[12288 + wslot * 32 + s * 16 + qq * 4 + r] = lsA[s][r];
    }
  }
  __syncthreads();
  if (qt == 0) {
    float ls[2][4];
#pragma unroll
    for (int s = 0; s < 2; ++s)
#pragma unroll
      for (int r = 0; r < 4; ++r) ls[s][r] = lsA[s][r];
#pragma unroll
    for (int j = 0; j < 3; ++j) {
      const int ws = j * 4 + wq;
#pragma unroll
      for (int dt = 0; dt < 4; ++dt)
#pragma unroll
        for (int r = 0; r < 4; ++r) {
          oc[0][dt][r] += kbuf[(dt * 4 + r) * 768 + ws * 64 + lane];
          oc[1][dt][r] += vbuf[(dt * 4 + r) * 768 + ws * 64 + lane];
        }
#pragma unroll
      for (int s = 0; s < 2; ++s)
#pragma unroll
        for (int r = 0; r < 4; ++r)
          ls[s][r] += kbuf[12288 + ws * 32 + s * 16 + qq * 4 + r];
    }
#pragma unroll
    for (int s = 0; s < 2; ++s) {
      float rinv[4];
#pragma unroll
      for (int r = 0; r < 4; ++r)
        rinv[r] = __builtin_amdgcn_rcpf(ls[s][r]);
#pragma unroll
      for (int dt = 0; dt < 4; ++dt) {
        const float bo = bout[g * DH + dt * 16 + col];
#pragma unroll
        for (int r = 0; r < 4; ++r)
          Out[(size_t)(n0 + wq * 32 + s * 16 + qq * 4 + r) * CDIM + g * DH +
              dt * 16 + col] = oc[s][dt][r] * rinv[r] + bo;
      }
    }
  }
}

extern "C" void kernel_launch(void* const* d_in, const int* in_sizes, int n_in,
                              void* d_out, int out_size, void* d_ws, size_t ws_size,
                              hipStream_t stream) {
  const float* in_x = (const float*)d_in[0];
  const float* rois = (const float*)d_in[1];
  const float* W0   = (const float*)d_in[2];
  const float* b0   = (const float*)d_in[3];
  const float* W1   = (const float*)d_in[4];
  const float* b1   = (const float*)d_in[5];
  const float* Wout = (const float*)d_in[6];  // (G,D,C) flat == (C,C) row-major
  const float* bout = (const float*)d_in[7];
  char* w8 = (char*)d_ws;

  // ws layout (22 MB):
  //   [0,4M)   xin_b (bf16 x) -> xb (gemm1 out; xin_b dead after gemm64<1>)
  //   [4,6M)   W0b   [6,8M) W1b   [8,10M) Woutb
  //   [10,14M) zT (bf16 V^T, key-permuted)
  //   [14,22M) biasb (bf16 iou+1e-6, key-permuted)
  short* xin_b = (short*)w8;
  short* W0b   = (short*)(w8 + ((size_t)4 << 20));
  short* W1b   = (short*)(w8 + ((size_t)6 << 20));
  short* Woutb = (short*)(w8 + ((size_t)8 << 20));
  short* zT    = (short*)(w8 + ((size_t)10 << 20));
  unsigned short* biasb = (unsigned short*)(w8 + ((size_t)14 << 20));
  short* xb  = xin_b;
  short* t0b = (short*)d_out;

  // 1) merged converts + iou bias (one launch)
  prep_kernel<<<2048, 512, 0, stream>>>(in_x, W0, W1, Wout, rois,
                                        xin_b, W0b, W1b, Woutb, biasb);
  // 2) fused 64x64 high-occupancy (+XCD swizzle): t0 and zT
  gemm64<1><<<dim3(32, 32), 256, 0, stream>>>(xin_b, W0b, Woutb, b0, t0b, zT);
  // 3) 64x64 high-occupancy (+XCD swizzle): xb = relu(t0)@W1^T + b1
  gemm64<0><<<dim3(16, 32), 256, 0, stream>>>(t0b, W1b, nullptr, b1, xb, nullptr);
  // 4) flash attention v6 (R7-verified champion, verbatim)
  attn_bias<<<dim3(16, 16), 1024, 0, stream>>>(xb, zT, biasb, bout,
                                               (float*)d_out);
}

// Round 13
// 178.929 us; speedup vs baseline: 1.1588x; 1.0096x over previous
//
#include <hip/hip_runtime.h>
#include <math.h>

// Problem constants
constexpr int NROI = 2048;  // N
constexpr int CDIM = 1024;  // C
constexpr int NG   = 16;    // groups
constexpr int DH   = 64;    // per-group dim

typedef __attribute__((ext_vector_type(8))) short short8;    // 8 bf16 (4 VGPRs)
typedef __attribute__((ext_vector_type(4))) float floatx4;   // MFMA C/D frag

#define MFMA_BF16(a, b, c) __builtin_amdgcn_mfma_f32_16x16x32_bf16((a), (b), (c), 0, 0, 0)

// fp32 -> bf16 round-to-nearest-even
__device__ __forceinline__ short f2bf(float f) {
  unsigned u = __float_as_uint(f);
  unsigned r = 0x7fffu + ((u >> 16) & 1u);
  return (short)((u + r) >> 16);
}
__device__ __forceinline__ float bf2f(unsigned short u) {
  return __uint_as_float(((unsigned)u) << 16);
}
__device__ __forceinline__ unsigned pack2(float a, float b) {
  return (unsigned)(unsigned short)f2bf(a) | ((unsigned)(unsigned short)f2bf(b) << 16);
}

// HW packed fp32->bf16 convert: dst.lo = bf16(lo), dst.hi = bf16(hi)
__device__ __forceinline__ unsigned cvtpk_bf16(float lo, float hi) {
  unsigned r;
  asm("v_cvt_pk_bf16_f32 %0, %1, %2" : "=v"(r) : "v"(lo), "v"(hi));
  return r;
}

// 2^x via v_exp_f32
__device__ __forceinline__ float fexp2(float x) {
#if __has_builtin(__builtin_amdgcn_exp2f)
  return __builtin_amdgcn_exp2f(x);
#else
  return __expf(x * 0.69314718056f);
#endif
}

// async global->LDS, 16B per lane; LDS dest = wave-uniform base + lane*16
typedef __attribute__((address_space(1))) void GV;
typedef __attribute__((address_space(3))) void LV;
__device__ __forceinline__ void gl2lds16(const void* g, void* l) {
  __builtin_amdgcn_global_load_lds((GV*)g, (LV*)l, 16, 0, 0);
}

// bf16 relu on a packed short8 (sign-bit based; exact)
__device__ __forceinline__ short8 brelu(short8 v) {
  union { short8 s; unsigned u[4]; } x; x.s = v;
#pragma unroll
  for (int i = 0; i < 4; ++i) {
    unsigned m = (x.u[i] >> 15) & 0x10001u;
    x.u[i] &= ~(m * 0xFFFFu);
  }
  return x.s;
}

// --- key-position permutation -------------------------------------------------
// Attention computes S^T = mfma(K, Q); P stays in-lane. The PV contraction is
// invariant under k-slot permutation, so V (zT) and the bias matrix store their
// key axis permuted so P packs into A-fragments with no cross-lane moves:
//   position p(k) within each 32-key block = ((k>>2)&3)*8 + ((k>>4)&1)*4 + (k&3)
__device__ __forceinline__ int keypos(int k) {
  return (k & ~31) | (((k >> 2) & 3) << 3) | (((k >> 4) & 1) << 2);
}

// ---------------- prep: fp32->bf16 converts + iou bias (single launch) ----------------
// grid 2048 x 512. First 524288 threads convert x; first 262144 also convert the
// three weight matrices; ALL 1,048,576 threads compute 4 iou entries each and
// store iou + 1e-6 as bf16, KEY-PERMUTED.
__global__ __launch_bounds__(512) void prep_kernel(
    const float* __restrict__ in_x, const float* __restrict__ W0,
    const float* __restrict__ W1, const float* __restrict__ Wout,
    const float* __restrict__ rois,
    short* __restrict__ xin_b, short* __restrict__ W0b,
    short* __restrict__ W1b, short* __restrict__ Woutb,
    unsigned short* __restrict__ biasb)
{
  const int gi = blockIdx.x * 512 + threadIdx.x;
  if (gi < 524288) {
    const float4 v = ((const float4*)in_x)[gi];
    uint2 u; u.x = pack2(v.x, v.y); u.y = pack2(v.z, v.w);
    ((uint2*)xin_b)[gi] = u;
  }
  if (gi < 262144) {
    float4 v = ((const float4*)W0)[gi];
    uint2 u; u.x = pack2(v.x, v.y); u.y = pack2(v.z, v.w);
    ((uint2*)W0b)[gi] = u;
    v = ((const float4*)W1)[gi];
    u.x = pack2(v.x, v.y); u.y = pack2(v.z, v.w);
    ((uint2*)W1b)[gi] = u;
    v = ((const float4*)Wout)[gi];
    u.x = pack2(v.x, v.y); u.y = pack2(v.z, v.w);
    ((uint2*)Woutb)[gi] = u;
  }
  // iou + 1e-6 (linear domain, verified math)
  const int q  = gi >> 9;
  const int k0 = (gi & 511) * 4;
  const float qx1 = rois[q * 5 + 1], qy1 = rois[q * 5 + 2];
  const float qx2 = rois[q * 5 + 3], qy2 = rois[q * 5 + 4];
  const float qa = (qx2 - qx1 + 1.f) * (qy2 - qy1 + 1.f);
  float v[4];
#pragma unroll
  for (int j = 0; j < 4; ++j) {
    const int k = k0 + j;
    const float kx1 = rois[k * 5 + 1], ky1 = rois[k * 5 + 2];
    const float kx2 = rois[k * 5 + 3], ky2 = rois[k * 5 + 4];
    const float ka = (kx2 - kx1 + 1.f) * (ky2 - ky1 + 1.f);
    float iw = fminf(qx2, kx2) - fmaxf(qx1, kx1) + 1.f;
    float ih = fminf(qy2, ky2) - fmaxf(qy1, ky1) + 1.f;
    iw = fmaxf(iw, 0.f); ih = fmaxf(ih, 0.f);
    const float inter = iw * ih;
    v[j] = inter * __builtin_amdgcn_rcpf(qa + ka - inter) + 1e-6f;
  }
  uint2 u; u.x = pack2(v[0], v[1]); u.y = pack2(v[2], v[3]);
  *(uint2*)&biasb[(size_t)q * NROI + keypos(k0)] = u;
}

// ---------------- 64x64 double-buffered GEMM, high occupancy (R5/R7-verified) ----------------
// FUSED=1: blockIdx.x<16 -> t0 = relu(x)@W0^T+b0 (row-major); else
//          zT = (x@Wout^T)^T (transposed out, KEY-PERMUTED rows). grid (32,32).
// FUSED=0: C = relu(A)@B^T + bias (row-major). grid (16,32).
template <int FUSED>
__global__ __launch_bounds__(256, 4) void gemm64(
    const short* __restrict__ A, const short* __restrict__ Ba,
    const short* __restrict__ Bb, const float* __restrict__ bias,
    short* __restrict__ outRM, short* __restrict__ outTR)
{
  __shared__ short As[2][8 * 512];
  __shared__ short Bs[2][8 * 512];
  const int t = threadIdx.x, w = t >> 6, lane = t & 63;
  const int wm = w >> 1, wn = w & 1;
  const int row0 = blockIdx.y * 64;
  bool isW0; int col0; const short* B;
  if (FUSED) {
    isW0 = blockIdx.x < 16;
    col0 = (blockIdx.x & 15) * 64;
    B = isW0 ? Ba : Bb;
  } else {
    isW0 = true; col0 = blockIdx.x * 64; B = Ba;
  }
  const bool doRelu = FUSED ? isW0 : true;
  const int rlo = lane & 15, khi = (lane >> 4) * 8;

  floatx4 acc[2][2];
#pragma unroll
  for (int i = 0; i < 2; ++i)
#pragma unroll
    for (int j = 0; j < 2; ++j) acc[i][j] = (floatx4){0.f, 0.f, 0.f, 0.f};

#pragma unroll
  for (int kh = 0; kh < 2; ++kh) {
    const int f = w * 2 + kh;
    gl2lds16(A + (size_t)(row0 + w * 16 + rlo) * CDIM + kh * 32 + khi, &As[0][f * 512]);
    gl2lds16(B + (size_t)(col0 + w * 16 + rlo) * CDIM + kh * 32 + khi, &Bs[0][f * 512]);
  }
  __syncthreads();

  for (int it = 0; it < 16; ++it) {
    const int p = it & 1;
    if (it < 15) {
      const int k1 = (it + 1) * 64;
#pragma unroll
      for (int kh = 0; kh < 2; ++kh) {
        const int f = w * 2 + kh;
        gl2lds16(A + (size_t)(row0 + w * 16 + rlo) * CDIM + k1 + kh * 32 + khi,
                 &As[1 - p][f * 512]);
        gl2lds16(B + (size_t)(col0 + w * 16 + rlo) * CDIM + k1 + kh * 32 + khi,
                 &Bs[1 - p][f * 512]);
      }
    }
#pragma unroll
    for (int kh = 0; kh < 2; ++kh) {
      short8 a[2], bf[2];
#pragma unroll
      for (int i = 0; i < 2; ++i) {
        a[i] = *(const short8*)&As[p][((wm * 2 + i) * 2 + kh) * 512 + lane * 8];
        if (doRelu) a[i] = brelu(a[i]);
      }
#pragma unroll
      for (int j = 0; j < 2; ++j)
        bf[j] = *(const short8*)&Bs[p][((wn * 2 + j) * 2 + kh) * 512 + lane * 8];
#pragma unroll
      for (int i = 0; i < 2; ++i)
#pragma unroll
        for (int j = 0; j < 2; ++j)
          acc[i][j] = MFMA_BF16(a[i], bf[j], acc[i][j]);
    }
    __syncthreads();
  }

  const int colL = lane & 15, qq = lane >> 4;
  if (!FUSED || isW0) {
    float bj[2];
    bj[0] = bias[col0 + wn * 32 + colL];
    bj[1] = bias[col0 + wn * 32 + 16 + colL];
#pragma unroll
    for (int i = 0; i < 2; ++i)
#pragma unroll
      for (int j = 0; j < 2; ++j)
#pragma unroll
        for (int r = 0; r < 4; ++r) {
          const int row = row0 + wm * 32 + i * 16 + qq * 4 + r;
          const int cc  = col0 + wn * 32 + j * 16 + colL;
          outRM[(size_t)row * CDIM + cc] = f2bf(acc[i][j][r] + bj[j]);
        }
  } else {
#pragma unroll
    for (int i = 0; i < 2; ++i)
#pragma unroll
      for (int j = 0; j < 2; ++j) {
        unsigned long long u =
            (unsigned long long)pack2(acc[i][j][0], acc[i][j][1]) |
            ((unsigned long long)pack2(acc[i][j][2], acc[i][j][3]) << 32);
        const int cc  = col0 + wn * 32 + j * 16 + colL;
        const int row = row0 + wm * 32 + i * 16 + qq * 4;   // 4-aligned key group
        *(unsigned long long*)&outTR[(size_t)cc * NROI + keypos(row)] = u;
      }
  }
}

// ---------------- MFMA flash attention, v6 (R7-verified champion, verbatim) ----------------
// 16 waves = 4 key-quarters x 4 q-waves, 32 q/wave, 8 iters, double-buffered
// K/V staging; softmax denominator via ones-column MFMA (lands in oc layout).
__global__ __launch_bounds__(1024) void attn_bias(
    const short* __restrict__ Xb,             // (N,C) bf16 embedded x
    const short* __restrict__ ZTb,            // (C,N) bf16 V, transposed, key-permuted
    const unsigned short* __restrict__ biasb, // (N,N) bf16 iou+1e-6, key-permuted
    const float* __restrict__ bout,
    float* __restrict__ Out)
{
  // XCD-aware decode: lin%8 = XCD. XCD x hosts groups {2x, 2x+1}.
  const int lin  = blockIdx.x + 16 * blockIdx.y;   // 256 blocks
  const int xcd  = lin & 7;
  const int slot = lin >> 3;                       // 0..31
  const int g    = 2 * xcd + (slot >> 4);
  const int n0   = (slot & 15) * 128;

  const int t    = threadIdx.x;
  const int w    = t >> 6;
  const int qt   = w >> 2;      // key quarter 0..3 -> keys [qt*512, qt*512+512)
  const int wq   = w & 3;       // q-pair index: q rows [n0+wq*32, n0+wq*32+32)
  const int lane = t & 63;
  const int col  = lane & 15;
  const int qq   = lane >> 4;
  const int rlo  = col, khi = qq * 8;

  __shared__ short Kq[4][2][4096];  // [quarter][buf][8 frags x 512]
  __shared__ short Vq[4][2][4096];

  // Q fragments for the two 16-q subtiles
  short8 qf[2][2];
#pragma unroll
  for (int s = 0; s < 2; ++s) {
    const size_t qoff = (size_t)(n0 + wq * 32 + s * 16 + col) * CDIM + g * DH;
    qf[s][0] = *(const short8*)(Xb + qoff + qq * 8);
    qf[s][1] = *(const short8*)(Xb + qoff + 32 + qq * 8);
  }

  // constant ones B-fragment (bf16 1.0) for the denominator MFMA
  short8 ONES;
#pragma unroll
  for (int i = 0; i < 8; ++i) ONES[i] = (short)0x3F80;

  floatx4 oc[2][4];   // [sub][dt]
#pragma unroll
  for (int s = 0; s < 2; ++s)
#pragma unroll
    for (int dt = 0; dt < 4; ++dt) oc[s][dt] = (floatx4){0.f, 0.f, 0.f, 0.f};
  floatx4 lsA[2];     // denominator, same (qq,r) layout as oc rows
  lsA[0] = (floatx4){0.f, 0.f, 0.f, 0.f};
  lsA[1] = (floatx4){0.f, 0.f, 0.f, 0.f};

  const int kb = qt * 512;   // this quarter's key base

  // stage iter 0: wave wq stages key-subtile wq (both k/key halves)
#pragma unroll
  for (int kh = 0; kh < 2; ++kh) {
    gl2lds16(Xb + (size_t)(kb + wq * 16 + rlo) * CDIM + g * DH + kh * 32 + khi,
             &Kq[qt][0][(wq * 2 + kh) * 512]);
    gl2lds16(ZTb + (size_t)(g * DH + wq * 16 + rlo) * NROI + kb + kh * 32 + khi,
             &Vq[qt][0][(wq * 2 + kh) * 512]);
  }
  __syncthreads();

  const unsigned short* bq0 =
      biasb + (size_t)(n0 + wq * 32 + col) * NROI + kb + qq * 8;
  const unsigned short* bq1 = bq0 + (size_t)16 * NROI;

  for (int it = 0; it < 8; ++it) {
    const int p  = it & 1;
    const int m0 = kb + it * 64;

    // bias: four coalesced 16B loads (two per q-subtile), issued early
    union { short8 s8[4]; unsigned short h[32]; } BU;
    BU.s8[0] = *(const short8*)(bq0 + it * 64);
    BU.s8[1] = *(const short8*)(bq0 + it * 64 + 32);
    BU.s8[2] = *(const short8*)(bq1 + it * 64);
    BU.s8[3] = *(const short8*)(bq1 + it * 64 + 32);

    if (it + 1 < 8) {
      const int m1 = m0 + 64;
#pragma unroll
      for (int kh = 0; kh < 2; ++kh) {
        gl2lds16(Xb + (size_t)(m1 + wq * 16 + rlo) * CDIM + g * DH + kh * 32 + khi,
                 &Kq[qt][1 - p][(wq * 2 + kh) * 512]);
        gl2lds16(ZTb + (size_t)(g * DH + wq * 16 + rlo) * NROI + m1 + kh * 32 + khi,
                 &Vq[qt][1 - p][(wq * 2 + kh) * 512]);
      }
    }

    // QK + softmax-weight + pack, per 16-key column-tile ct; each K-frag pair
    // feeds BOTH q-subtiles (the LDS-read amortization).
    union { short8 s; unsigned u[4]; } U[2][2];   // [sub][kslot-half]
#pragma unroll
    for (int ct = 0; ct < 4; ++ct) {
      const short8 k0 = *(const short8*)&Kq[qt][p][(ct * 2 + 0) * 512 + lane * 8];
      const short8 k1 = *(const short8*)&Kq[qt][p][(ct * 2 + 1) * 512 + lane * 8];
#pragma unroll
      for (int s = 0; s < 2; ++s) {
        floatx4 z4 = (floatx4){0.f, 0.f, 0.f, 0.f};
        z4 = MFMA_BF16(k0, qf[s][0], z4);
        z4 = MFMA_BF16(k1, qf[s][1], z4);
        float pv0 = fexp2(z4[0] * 0.18033688011f) * bf2f(BU.h[s * 16 + ct * 4 + 0]);
        float pv1 = fexp2(z4[1] * 0.18033688011f) * bf2f(BU.h[s * 16 + ct * 4 + 1]);
        float pv2 = fexp2(z4[2] * 0.18033688011f) * bf2f(BU.h[s * 16 + ct * 4 + 2]);
        float pv3 = fexp2(z4[3] * 0.18033688011f) * bf2f(BU.h[s * 16 + ct * 4 + 3]);
        U[s][ct >> 1].u[(ct & 1) * 2 + 0] = cvtpk_bf16(pv0, pv1);
        U[s][ct >> 1].u[(ct & 1) * 2 + 1] = cvtpk_bf16(pv2, pv3);
      }
    }

    // denominator: rowsum of packed P via ones-column MFMA (static indices)
    lsA[0] = MFMA_BF16(U[0][0].s, ONES, lsA[0]);
    lsA[0] = MFMA_BF16(U[0][1].s, ONES, lsA[0]);
    lsA[1] = MFMA_BF16(U[1][0].s, ONES, lsA[1]);
    lsA[1] = MFMA_BF16(U[1][1].s, ONES, lsA[1]);

    // PV: each V-frag pair feeds both q-subtiles
#pragma unroll
    for (int dt = 0; dt < 4; ++dt) {
      const short8 v0 = *(const short8*)&Vq[qt][p][(dt * 2 + 0) * 512 + lane * 8];
      const short8 v1 = *(const short8*)&Vq[qt][p][(dt * 2 + 1) * 512 + lane * 8];
#pragma unroll
      for (int s = 0; s < 2; ++s) {
        oc[s][dt] = MFMA_BF16(U[s][0].s, v0, oc[s][dt]);
        oc[s][dt] = MFMA_BF16(U[s][1].s, v1, oc[s][dt]);
      }
    }
    __syncthreads();
  }

  // cross-quarter combine via LDS (K/V buffers dead). oc: lane-contiguous
  // [elem][wave12][lane] (conflict-free). lsA[s][r] is identical across the 16
  // lanes of a qq-group, so col==0 lanes store 32 floats per wave; readers hit
  // the same address per qq-group -> LDS broadcast.
  float* kbuf = (float*)&Kq[0][0][0];   // 16384 floats
  float* vbuf = (float*)&Vq[0][0][0];   // 16384 floats
  const int wslot = (qt - 1) * 4 + wq;  // 0..11 for quarters 1..3
  if (qt != 0) {
#pragma unroll
    for (int dt = 0; dt < 4; ++dt)
#pragma unroll
      for (int r = 0; r < 4; ++r) {
        kbuf[(dt * 4 + r) * 768 + wslot * 64 + lane] = oc[0][dt][r];
        vbuf[(dt * 4 + r) * 768 + wslot * 64 + lane] = oc[1][dt][r];
      }
    if (col == 0) {
#pragma unroll
      for (int s = 0; s < 2; ++s)
#pragma unroll
        for (int r = 0; r < 4; ++r)
          kbuf[12288 + wslot * 32 + s * 16 + qq * 4 + r] = lsA[s][r];
    }
  }
  __syncthreads();
  if (qt == 0) {
    float ls[2][4];
#pragma unroll
    for (int s = 0; s < 2; ++s)
#pragma unroll
      for (int r = 0; r < 4; ++r) ls[s][r] = lsA[s][r];
#pragma unroll
    for (int j = 0; j < 3; ++j) {
      const int ws = j * 4 + wq;
#pragma unroll
      for (int dt = 0; dt < 4; ++dt)
#pragma unroll
        for (int r = 0; r < 4; ++r) {
          oc[0][dt][r] += kbuf[(dt * 4 + r) * 768 + ws * 64 + lane];
          oc[1][dt][r] += vbuf[(dt * 4 + r) * 768 + ws * 64 + lane];
        }
#pragma unroll
      for (int s = 0; s < 2; ++s)
#pragma unroll
        for (int r = 0; r < 4; ++r)
          ls[s][r] += kbuf[12288 + ws * 32 + s * 16 + qq * 4 + r];
    }
#pragma unroll
    for (int s = 0; s < 2; ++s) {
      float rinv[4];
#pragma unroll
      for (int r = 0; r < 4; ++r)
        rinv[r] = __builtin_amdgcn_rcpf(ls[s][r]);
#pragma unroll
      for (int dt = 0; dt < 4; ++dt) {
        const float bo = bout[g * DH + dt * 16 + col];
#pragma unroll
        for (int r = 0; r < 4; ++r)
          Out[(size_t)(n0 + wq * 32 + s * 16 + qq * 4 + r) * CDIM + g * DH +
              dt * 16 + col] = oc[s][dt][r] * rinv[r] + bo;
      }
    }
  }
}

extern "C" void kernel_launch(void* const* d_in, const int* in_sizes, int n_in,
                              void* d_out, int out_size, void* d_ws, size_t ws_size,
                              hipStream_t stream) {
  const float* in_x = (const float*)d_in[0];
  const float* rois = (const float*)d_in[1];
  const float* W0   = (const float*)d_in[2];
  const float* b0   = (const float*)d_in[3];
  const float* W1   = (const float*)d_in[4];
  const float* b1   = (const float*)d_in[5];
  const float* Wout = (const float*)d_in[6];  // (G,D,C) flat == (C,C) row-major
  const float* bout = (const float*)d_in[7];
  char* w8 = (char*)d_ws;

  // ws layout (22 MB):
  //   [0,4M)   xin_b (bf16 x) -> xb (gemm1 out; xin_b dead after gemm64<1>)
  //   [4,6M)   W0b   [6,8M) W1b   [8,10M) Woutb
  //   [10,14M) zT (bf16 V^T, key-permuted)
  //   [14,22M) biasb (bf16 iou+1e-6, key-permuted)
  short* xin_b = (short*)w8;
  short* W0b   = (short*)(w8 + ((size_t)4 << 20));
  short* W1b   = (short*)(w8 + ((size_t)6 << 20));
  short* Woutb = (short*)(w8 + ((size_t)8 << 20));
  short* zT    = (short*)(w8 + ((size_t)10 << 20));
  unsigned short* biasb = (unsigned short*)(w8 + ((size_t)14 << 20));
  short* xb  = xin_b;
  short* t0b = (short*)d_out;

  // 1) merged converts + iou bias (one launch)
  prep_kernel<<<2048, 512, 0, stream>>>(in_x, W0, W1, Wout, rois,
                                        xin_b, W0b, W1b, Woutb, biasb);
  // 2) fused 64x64 high-occupancy: t0 = relu(x)@W0^T+b0 and zT = (x@Wout^T)^T
  gemm64<1><<<dim3(32, 32), 256, 0, stream>>>(xin_b, W0b, Woutb, b0, t0b, zT);
  // 3) 64x64 high-occupancy: xb = relu(t0)@W1^T + b1
  gemm64<0><<<dim3(16, 32), 256, 0, stream>>>(t0b, W1b, nullptr, b1, xb, nullptr);
  // 4) flash attention v6 (R7-verified champion, verbatim)
  attn_bias<<<dim3(16, 16), 1024, 0, stream>>>(xb, zT, biasb, bout,
                                               (float*)d_out);
}